// Round 5
// baseline (323.505 us; speedup 1.0000x reference)
//
#include <hip/hip_runtime.h>

typedef __attribute__((ext_vector_type(8))) short bf16x8;
typedef __attribute__((ext_vector_type(8))) unsigned short ushort8;
typedef __attribute__((ext_vector_type(4))) float floatx4;

static __device__ __forceinline__ unsigned short f2b(float f) {
  union { float f; unsigned int i; } v; v.f = f;
  unsigned int x = v.i;
  return (unsigned short)((x + 0x7fffu + ((x >> 16) & 1u)) >> 16);
}

#define GLDS(gp, lp) \
  __builtin_amdgcn_global_load_lds( \
      (const __attribute__((address_space(1))) unsigned int*)(gp), \
      (__attribute__((address_space(3))) unsigned int*)(lp), 16, 0, 0)

static __device__ __forceinline__ void swizzle_mn(int lin, int Mb, int Nb,
                                                  int& m_idx, int& n_idx) {
  if ((Mb & 7) == 0) {
    int xcd = lin & 7;
    int idx = lin >> 3;
    int nstrips = Mb >> 3;
    m_idx = (idx % nstrips) * 8 + xcd;
    n_idx = idx / nstrips;
  } else {
    m_idx = lin % Mb;
    n_idx = lin / Mb;
  }
}

// ---------------- zero fp32 buffer (for atomic split-K combine) -----------------
__global__ void zero_f32(float* __restrict__ p) {
  int i = (blockIdx.x * 256 + threadIdx.x) * 4;
  *(float4*)(p + i) = make_float4(0.f, 0.f, 0.f, 0.f);
}

// -------- fused router + fp32->bf16 convert (one pass over hidden_states) ------
__global__ __launch_bounds__(256) void router_cvt(
    const float* __restrict__ X, const float* __restrict__ RW,
    float* __restrict__ cw, unsigned short* __restrict__ Xb) {
  const int tid = threadIdx.x;
  const int wid = tid >> 6, lane = tid & 63;
  const int t = blockIdx.x * 4 + wid;
  const float* xp = X + (size_t)t * 1024;
  unsigned short* xo = Xb + (size_t)t * 1024;
  float acc[8];
#pragma unroll
  for (int e = 0; e < 8; e++) acc[e] = 0.f;
#pragma unroll
  for (int i = 0; i < 4; i++) {
    const int d0 = i * 256 + lane * 4;
    float4 v = *(const float4*)(xp + d0);
    ushort4 o;
    o.x = f2b(v.x); o.y = f2b(v.y); o.z = f2b(v.z); o.w = f2b(v.w);
    *(ushort4*)(xo + d0) = o;
    const float xv[4] = {v.x, v.y, v.z, v.w};
#pragma unroll
    for (int j = 0; j < 4; j++) {
      const float* r = RW + (size_t)(d0 + j) * 8;
      float4 r0 = *(const float4*)r;
      float4 r1 = *(const float4*)(r + 4);
      acc[0] += xv[j] * r0.x; acc[1] += xv[j] * r0.y;
      acc[2] += xv[j] * r0.z; acc[3] += xv[j] * r0.w;
      acc[4] += xv[j] * r1.x; acc[5] += xv[j] * r1.y;
      acc[6] += xv[j] * r1.z; acc[7] += xv[j] * r1.w;
    }
  }
#pragma unroll
  for (int m = 1; m < 64; m <<= 1) {
#pragma unroll
    for (int e = 0; e < 8; e++) acc[e] += __shfl_xor(acc[e], m);
  }
  if (lane == 0) {
    float mx = acc[0];
#pragma unroll
    for (int e = 1; e < 8; e++) mx = fmaxf(mx, acc[e]);
    float prob[8], s = 0.f;
#pragma unroll
    for (int e = 0; e < 8; e++) { prob[e] = expf(acc[e] - mx); s += prob[e]; }
    float inv = 1.f / s;
#pragma unroll
    for (int e = 0; e < 8; e++) prob[e] *= inv;
    int m1 = 0;
#pragma unroll
    for (int e = 1; e < 8; e++) if (prob[e] < prob[m1]) m1 = e;
    int m2 = -1;
#pragma unroll
    for (int e = 0; e < 8; e++)
      if (e != m1 && (m2 < 0 || prob[e] < prob[m2])) m2 = e;
#pragma unroll
    for (int e = 0; e < 8; e++)
      cw[(size_t)t * 8 + e] = (e == m1 || e == m2) ? 0.f : prob[e];
  }
}

// -------- all 27 weight transposes, one launch: fp32 [K,N] -> bf16 [N,K] --------
__global__ __launch_bounds__(256) void transpose_all(
    const float* __restrict__ wg, const float* __restrict__ wu,
    const float* __restrict__ wd, const float* __restrict__ wsg,
    const float* __restrict__ wsu, const float* __restrict__ wsd,
    unsigned short* __restrict__ wgT, unsigned short* __restrict__ wuT,
    unsigned short* __restrict__ wdT, unsigned short* __restrict__ wsgT,
    unsigned short* __restrict__ wsuT, unsigned short* __restrict__ wsdT) {
  __shared__ __align__(16) unsigned short T[64 * 68];
  const int z = blockIdx.z;
  const float* src; unsigned short* dst; int K, N;
  if (z < 8)       { src = wg  + (size_t)z * 1024 * 512;        dst = wgT + (size_t)z * 512 * 1024;        K = 1024; N = 512; }
  else if (z < 16) { src = wu  + (size_t)(z - 8) * 1024 * 512;  dst = wuT + (size_t)(z - 8) * 512 * 1024;  K = 1024; N = 512; }
  else if (z < 24) { src = wd  + (size_t)(z - 16) * 512 * 1024; dst = wdT + (size_t)(z - 16) * 1024 * 512; K = 512;  N = 1024; }
  else if (z == 24){ src = wsg; dst = wsgT; K = 1024; N = 1024; }
  else if (z == 25){ src = wsu; dst = wsuT; K = 1024; N = 1024; }
  else             { src = wsd; dst = wsdT; K = 1024; N = 1024; }
  const int bn = blockIdx.x * 64, bk = blockIdx.y * 64;
  if (bn >= N || bk >= K) return;
  const int tid = threadIdx.x;
  {
    const int r = tid >> 4;            // 0..15
    const int c = (tid & 15) * 4;      // 0..60
#pragma unroll
    for (int i = 0; i < 4; i++) {
      const int rr = r + i * 16;
      float4 v = *(const float4*)(src + (size_t)(bk + rr) * N + bn + c);
      ushort4 o;
      o.x = f2b(v.x); o.y = f2b(v.y); o.z = f2b(v.z); o.w = f2b(v.w);
      *(ushort4*)(&T[rr * 68 + c]) = o;
    }
  }
  __syncthreads();
  {
    const int n_ = tid >> 3;           // 0..31
    const int k0 = (tid & 7) * 8;      // 0..56
#pragma unroll
    for (int p = 0; p < 2; p++) {
      const int n = n_ + p * 32;
      ushort8 o;
#pragma unroll
      for (int j = 0; j < 8; j++) o[j] = T[(k0 + j) * 68 + n];
      *(ushort8*)(dst + (size_t)(bn + n) * K + bk + k0) = o;
    }
  }
}

// ------------- fused gate+up GEMM: H = cw * silu(X@Wg) * (X@Wu) -----------------
// (frozen since round 1/4: BM=256, BN=128, BK=64, 8 waves, dbuf 128KB LDS,
// 4 phases/K-tile, counted vmcnt(6), XOR swizzle, raw s_barrier, setprio,
// XCD n-ownership swizzle.)
#define VMCNT(N) asm volatile("s_waitcnt vmcnt(" #N ")" ::: "memory")
#define BARS() do { __builtin_amdgcn_s_barrier(); \
                    __builtin_amdgcn_sched_barrier(0); } while (0)

#define STG_I0(K, BS) do { \
  GLDS(a0 + (K),          sm + (BS) + wid * 512); \
  GLDS(a0 + (K) + 131072, sm + (BS) + 8192 + wid * 512); } while (0)
#define STG_I1(K, BS) do { \
  GLDS(bg0 + (K),        sm + (BS) + 16384 + wid * 1024); \
  GLDS(bg0 + (K) + 8192, sm + (BS) + 16384 + wid * 1024 + 512); } while (0)
#define STG_I2(K, BS) do { \
  GLDS(bu0 + (K),        sm + (BS) + 24576 + wid * 1024); \
  GLDS(bu0 + (K) + 8192, sm + (BS) + 24576 + wid * 1024 + 512); } while (0)
#define STG_I3(K, BS) do { \
  GLDS(a0 + (K) + 65536,  sm + (BS) + 4096 + wid * 512); \
  GLDS(a0 + (K) + 196608, sm + (BS) + 12288 + wid * 512); } while (0)

#define READ_A(DST, DB, H) do { _Pragma("unroll") \
  for (int mf = 0; mf < 4; ++mf) { \
    const int row_ = wm * 128 + (H) * 64 + mf * 16 + lr; \
    const int rb_ = (DB) + row_ * 64; const int rx_ = row_ & 7; \
    DST[mf][0] = *(const bf16x8*)(sm + rb_ + ((quad ^ rx_) << 3)); \
    DST[mf][1] = *(const bf16x8*)(sm + rb_ + (((4 + quad) ^ rx_) << 3)); \
  } } while (0)

#define READ_B(DST, DB, RG) do { _Pragma("unroll") \
  for (int nf = 0; nf < 2; ++nf) { \
    const int row_ = wn * 32 + nf * 16 + lr; \
    const int rb_ = (DB) + (RG) + row_ * 64; const int rx_ = row_ & 7; \
    DST[nf][0] = *(const bf16x8*)(sm + rb_ + ((quad ^ rx_) << 3)); \
    DST[nf][1] = *(const bf16x8*)(sm + rb_ + (((4 + quad) ^ rx_) << 3)); \
  } } while (0)

#define MM(ACC, AF, BF) do { \
  __builtin_amdgcn_s_setprio(1); \
  _Pragma("unroll") \
  for (int mf = 0; mf < 4; ++mf) { _Pragma("unroll") \
    for (int nf = 0; nf < 2; ++nf) { \
      ACC[mf][nf] = __builtin_amdgcn_mfma_f32_16x16x32_bf16( \
          AF[mf][0], BF[nf][0], ACC[mf][nf], 0, 0, 0); \
      ACC[mf][nf] = __builtin_amdgcn_mfma_f32_16x16x32_bf16( \
          AF[mf][1], BF[nf][1], ACC[mf][nf], 0, 0, 0); \
    } } \
  __builtin_amdgcn_s_setprio(0); } while (0)

__global__ __launch_bounds__(512, 2) void gemm_gu_fused(
    const unsigned short* __restrict__ X,
    const unsigned short* __restrict__ WgTe,
    const unsigned short* __restrict__ WgTs,
    const unsigned short* __restrict__ WuTe,
    const unsigned short* __restrict__ WuTs,
    unsigned short* __restrict__ H,
    const float* __restrict__ cw, int Mb) {
  __shared__ __align__(16) unsigned short sm[65536];
  const int tid = threadIdx.x;
  const int wid = tid >> 6, lane = tid & 63;
  const int lr = lane & 15, quad = lane >> 4;
  const int wm = wid >> 2, wn = wid & 3;

  int m_idx, n_idx;
  {
    const int lin = blockIdx.x;
    const int xcd = lin & 7;
    const int idx = lin >> 3;          // [0, Mb*5)
    m_idx = idx / 5;
    n_idx = xcd * 5 + (idx - m_idx * 5);
  }
  const int m0 = m_idx * 256;
  const int n0 = n_idx * 128;

  const unsigned short *Bg, *Bu;
  int eidx = -1;
  if (n0 < 4096) {
    eidx = n0 >> 9;
    size_t off = ((size_t)eidx * 512 + (n0 & 511)) * 1024;
    Bg = WgTe + off; Bu = WuTe + off;
  } else {
    size_t off = (size_t)(n0 - 4096) * 1024;
    Bg = WgTs + off; Bu = WuTs + off;
  }

  const int grow8 = lane >> 3;
  const int gcol = ((lane & 7) ^ grow8) << 3;
  const unsigned short* a0 =
      X + (size_t)(m0 + wid * 8 + grow8) * 1024 + gcol;
  const unsigned short* bg0 =
      Bg + (size_t)(wid * 16 + grow8) * 1024 + gcol;
  const unsigned short* bu0 =
      Bu + (size_t)(wid * 16 + grow8) * 1024 + gcol;

  floatx4 gg[2][4][2], uu[2][4][2];
#pragma unroll
  for (int h = 0; h < 2; h++)
#pragma unroll
    for (int mf = 0; mf < 4; mf++)
#pragma unroll
      for (int nf = 0; nf < 2; nf++) {
        gg[h][mf][nf] = (floatx4)0.f;
        uu[h][mf][nf] = (floatx4)0.f;
      }

  bf16x8 fA0[4][2], fA1[4][2], fBg[2][2], fBu[2][2];

  STG_I0(0, 0); STG_I1(0, 0); STG_I2(0, 0); STG_I3(0, 0);

  for (int t = 0; t < 15; ++t) {
    const int db = (t & 1) << 15;
    const int nb = 32768 - db;
    const int kn = (t + 1) * 64;
    STG_I0(kn, nb);
    VMCNT(6); BARS();
    READ_A(fA0, db, 0);
    READ_B(fBg, db, 16384);
    MM(gg[0], fA0, fBg);
    STG_I1(kn, nb);
    VMCNT(6); BARS();
    READ_B(fBu, db, 24576);
    MM(uu[0], fA0, fBu);
    STG_I2(kn, nb);
    VMCNT(6); BARS();
    READ_A(fA1, db, 1);
    MM(gg[1], fA1, fBg);
    STG_I3(kn, nb);
    BARS();
    MM(uu[1], fA1, fBu);
  }
  {
    const int db = 32768;
    VMCNT(4); BARS();
    READ_A(fA0, db, 0);
    READ_B(fBg, db, 16384);
    MM(gg[0], fA0, fBg);
    VMCNT(2); BARS();
    READ_B(fBu, db, 24576);
    MM(uu[0], fA0, fBu);
    VMCNT(0); BARS();
    READ_A(fA1, db, 1);
    MM(gg[1], fA1, fBg);
    MM(uu[1], fA1, fBu);
  }

#pragma unroll
  for (int h = 0; h < 2; h++) {
#pragma unroll
    for (int mf = 0; mf < 4; mf++) {
#pragma unroll
      for (int nf = 0; nf < 2; nf++) {
#pragma unroll
        for (int r = 0; r < 4; r++) {
          int row = m0 + wm * 128 + h * 64 + mf * 16 + quad * 4 + r;
          int col = n0 + wn * 32 + nf * 16 + lr;
          float g = gg[h][mf][nf][r];
          float u = uu[h][mf][nf][r];
          float s = (eidx >= 0) ? cw[(size_t)row * 8 + eidx] : 1.0f;
          float silu = g / (1.0f + __expf(-g));
          H[(size_t)row * 5120 + col] = f2b(s * silu * u);
        }
      }
    }
  }
}

// ---------------- down GEMM: Y[rows,1024] += H[rows,5120] @ Wd_cat --------------
// Split-K=2 (round 5): BM=128, BN=128, BK=64, each block does K=2560 (40 tiles).
// Grid = 2s x 32m x 8n = 512 blocks -> 2 blocks/CU (dbuf 64KB LDS,
// launch_bounds(512,4)); co-resident blocks cover each other's barrier/staging
// stalls (m97 implicit-overlap lesson; round-4 showed locality alone is not the
// binding constraint). Counted vmcnt(4) depth-1, two raw barriers/tile, XOR
// chunk-swizzle. Epilogue: unsafeAtomicAdd (global_atomic_add_f32, disjoint
// k-halves, coalesced) onto zero_f32-cleared Y.
#define DN_STG(KN, SBUF) do { \
  GLDS(Ha + (size_t)(KN),          smD + (SBUF) + wid * 512); \
  GLDS(Ha + (size_t)(KN) + 327680, smD + (SBUF) + 4096 + wid * 512); \
  const unsigned short *b0p_, *b1p_; \
  if ((KN) < 4096) { \
    const unsigned short* be_ = WdTe + ((size_t)((KN) >> 9)) * (1024 * 512) + ((KN) & 511); \
    b0p_ = be_ + (size_t)bn0 * 512 + gcol; \
    b1p_ = be_ + (size_t)(bn0 + 64) * 512 + gcol; \
  } else { \
    b0p_ = WdTs + (size_t)bn0 * 1024 + ((KN) - 4096) + gcol; \
    b1p_ = WdTs + (size_t)(bn0 + 64) * 1024 + ((KN) - 4096) + gcol; \
  } \
  GLDS(b0p_, smD + (SBUF) + 8192 + wid * 512); \
  GLDS(b1p_, smD + (SBUF) + 12288 + wid * 512); } while (0)

__global__ __launch_bounds__(512, 4) void gemm_down(
    const unsigned short* __restrict__ H,
    const unsigned short* __restrict__ WdTe,
    const unsigned short* __restrict__ WdTs,
    float* __restrict__ Y, int Mb) {
  // 2 buffers x 16384 shorts: per buffer A [0,8192), B [8192,16384)
  __shared__ __align__(16) unsigned short smD[32768];
  const int tid = threadIdx.x;
  const int wid = tid >> 6, lane = tid & 63;
  const int lr = lane & 15, quad = lane >> 4;
  const int wm = wid >> 2, wn = wid & 3;
  const int s = blockIdx.x & 1;            // K-split half
  int m_idx, n_idx;
  swizzle_mn(blockIdx.x >> 1, Mb, 8, m_idx, n_idx);
  const int m0 = m_idx * 128;
  const int n0 = n_idx * 128;
  const int t0 = s * 40;                   // first K-tile of this half

  const int grow8 = lane >> 3;
  const int gcol = ((lane & 7) ^ grow8) << 3;
  const unsigned short* Ha = H + (size_t)(m0 + wid * 8 + grow8) * 5120 + gcol;
  const int bn0 = n0 + wid * 8 + grow8;

  floatx4 acc[4][2];
#pragma unroll
  for (int i = 0; i < 4; i++)
#pragma unroll
    for (int j = 0; j < 2; j++) acc[i][j] = (floatx4)0.f;

  // prologue: first tile -> buffer 0
  DN_STG(t0 * 64, 0);

  for (int tt = 0; tt < 40; ++tt) {
    const int db = (tt & 1) * 16384;
    const int nb = 16384 - db;
    if (tt < 39) {
      DN_STG((t0 + tt + 1) * 64, nb);
      VMCNT(4);
    } else {
      VMCNT(0);
    }
    BARS();
    bf16x8 af_[4][2], bf_[2][2];
#pragma unroll
    for (int mt = 0; mt < 4; ++mt) {
      const int row_ = wm * 64 + mt * 16 + lr;
      const int rb_ = db + row_ * 64; const int rx_ = row_ & 7;
      af_[mt][0] = *(const bf16x8*)(smD + rb_ + ((quad ^ rx_) << 3));
      af_[mt][1] = *(const bf16x8*)(smD + rb_ + (((4 + quad) ^ rx_) << 3));
    }
#pragma unroll
    for (int nt = 0; nt < 2; ++nt) {
      const int row_ = wn * 32 + nt * 16 + lr;
      const int rb_ = db + 8192 + row_ * 64; const int rx_ = row_ & 7;
      bf_[nt][0] = *(const bf16x8*)(smD + rb_ + ((quad ^ rx_) << 3));
      bf_[nt][1] = *(const bf16x8*)(smD + rb_ + (((4 + quad) ^ rx_) << 3));
    }
    __builtin_amdgcn_s_setprio(1);
#pragma unroll
    for (int kt = 0; kt < 2; ++kt)
#pragma unroll
      for (int mt = 0; mt < 4; ++mt)
#pragma unroll
        for (int nt = 0; nt < 2; ++nt)
          acc[mt][nt] = __builtin_amdgcn_mfma_f32_16x16x32_bf16(
              af_[mt][kt], bf_[nt][kt], acc[mt][nt], 0, 0, 0);
    __builtin_amdgcn_s_setprio(0);
    BARS();   // release read buffer before next iteration's STG overwrites it
  }

#pragma unroll
  for (int mt = 0; mt < 4; mt++)
#pragma unroll
    for (int nt = 0; nt < 2; nt++)
#pragma unroll
      for (int r = 0; r < 4; r++) {
        int row = m0 + wm * 64 + mt * 16 + quad * 4 + r;
        int col = n0 + wn * 32 + nt * 16 + lr;
        unsafeAtomicAdd(&Y[(size_t)row * 1024 + col], acc[mt][nt][r]);
      }
}

extern "C" void kernel_launch(void* const* d_in, const int* in_sizes, int n_in,
                              void* d_out, int out_size, void* d_ws, size_t ws_size,
                              hipStream_t stream) {
  const float* hs  = (const float*)d_in[0];
  const float* rw  = (const float*)d_in[1];
  const float* wg  = (const float*)d_in[2];
  const float* wu  = (const float*)d_in[3];
  const float* wd  = (const float*)d_in[4];
  const float* wsg = (const float*)d_in[5];
  const float* wsu = (const float*)d_in[6];
  const float* wsd = (const float*)d_in[7];
  float* out = (float*)d_out;

  char* p = (char*)d_ws;
  float* cw = (float*)p;                    p += (size_t)4096 * 8 * 4;
  unsigned short* Xb   = (unsigned short*)p; p += (size_t)4096 * 1024 * 2;
  unsigned short* wgT  = (unsigned short*)p; p += (size_t)8 * 512 * 1024 * 2;
  unsigned short* wuT  = (unsigned short*)p; p += (size_t)8 * 512 * 1024 * 2;
  unsigned short* wsgT = (unsigned short*)p; p += (size_t)1024 * 1024 * 2;
  unsigned short* wsuT = (unsigned short*)p; p += (size_t)1024 * 1024 * 2;
  unsigned short* wdT  = (unsigned short*)p; p += (size_t)8 * 1024 * 512 * 2;
  unsigned short* wsdT = (unsigned short*)p; p += (size_t)1024 * 1024 * 2;
  unsigned short* GH   = (unsigned short*)p;
  const size_t base_bytes = (size_t)(p - (char*)d_ws);

  int chunks = 8;
  for (int c = 1; c <= 8; c *= 2) {
    size_t gh_bytes = ((size_t)4096 / c) * 5120 * 2;
    if (base_bytes + gh_bytes <= ws_size) { chunks = c; break; }
  }
  const int rows = 4096 / chunks;
  const int Mb = rows / 128;     // gemm_down 128-row tiles
  const int MbG = rows / 256;    // gemm_gu 256-row tiles

  router_cvt<<<1024, 256, 0, stream>>>(hs, rw, cw, Xb);
  transpose_all<<<dim3(16, 16, 27), 256, 0, stream>>>(
      wg, wu, wd, wsg, wsu, wsd, wgT, wuT, wdT, wsgT, wsuT, wsdT);

  for (int c = 0; c < chunks; c++) {
    const unsigned short* Xc = Xb + (size_t)c * rows * 1024;
    const float* cwc = cw + (size_t)c * rows * 8;
    float* outc = out + (size_t)c * rows * 1024;
    zero_f32<<<rows, 256, 0, stream>>>(outc);
    gemm_gu_fused<<<MbG * 40, 512, 0, stream>>>(
        Xc, wgT, wsgT, wuT, wsuT, GH, cwc, MbG);
    gemm_down<<<Mb * 16, 512, 0, stream>>>(GH, wdT, wsdT, outc, Mb);
  }
}

// Round 7
// 297.510 us; speedup vs baseline: 1.0874x; 1.0874x over previous
//
#include <hip/hip_runtime.h>

typedef __attribute__((ext_vector_type(8))) short bf16x8;
typedef __attribute__((ext_vector_type(8))) unsigned short ushort8;
typedef __attribute__((ext_vector_type(4))) float floatx4;

static __device__ __forceinline__ unsigned short f2b(float f) {
  union { float f; unsigned int i; } v; v.f = f;
  unsigned int x = v.i;
  return (unsigned short)((x + 0x7fffu + ((x >> 16) & 1u)) >> 16);
}

#define GLDS(gp, lp) \
  __builtin_amdgcn_global_load_lds( \
      (const __attribute__((address_space(1))) unsigned int*)(gp), \
      (__attribute__((address_space(3))) unsigned int*)(lp), 16, 0, 0)

static __device__ __forceinline__ void swizzle_mn(int lin, int Mb, int Nb,
                                                  int& m_idx, int& n_idx) {
  if ((Mb & 7) == 0) {
    int xcd = lin & 7;
    int idx = lin >> 3;
    int nstrips = Mb >> 3;
    m_idx = (idx % nstrips) * 8 + xcd;
    n_idx = idx / nstrips;
  } else {
    m_idx = lin % Mb;
    n_idx = lin / Mb;
  }
}

// -------- fused router + fp32->bf16 convert (one pass over hidden_states) ------
__global__ __launch_bounds__(256) void router_cvt(
    const float* __restrict__ X, const float* __restrict__ RW,
    float* __restrict__ cw, unsigned short* __restrict__ Xb) {
  const int tid = threadIdx.x;
  const int wid = tid >> 6, lane = tid & 63;
  const int t = blockIdx.x * 4 + wid;
  const float* xp = X + (size_t)t * 1024;
  unsigned short* xo = Xb + (size_t)t * 1024;
  float acc[8];
#pragma unroll
  for (int e = 0; e < 8; e++) acc[e] = 0.f;
#pragma unroll
  for (int i = 0; i < 4; i++) {
    const int d0 = i * 256 + lane * 4;
    float4 v = *(const float4*)(xp + d0);
    ushort4 o;
    o.x = f2b(v.x); o.y = f2b(v.y); o.z = f2b(v.z); o.w = f2b(v.w);
    *(ushort4*)(xo + d0) = o;
    const float xv[4] = {v.x, v.y, v.z, v.w};
#pragma unroll
    for (int j = 0; j < 4; j++) {
      const float* r = RW + (size_t)(d0 + j) * 8;
      float4 r0 = *(const float4*)r;
      float4 r1 = *(const float4*)(r + 4);
      acc[0] += xv[j] * r0.x; acc[1] += xv[j] * r0.y;
      acc[2] += xv[j] * r0.z; acc[3] += xv[j] * r0.w;
      acc[4] += xv[j] * r1.x; acc[5] += xv[j] * r1.y;
      acc[6] += xv[j] * r1.z; acc[7] += xv[j] * r1.w;
    }
  }
#pragma unroll
  for (int m = 1; m < 64; m <<= 1) {
#pragma unroll
    for (int e = 0; e < 8; e++) acc[e] += __shfl_xor(acc[e], m);
  }
  if (lane == 0) {
    float mx = acc[0];
#pragma unroll
    for (int e = 1; e < 8; e++) mx = fmaxf(mx, acc[e]);
    float prob[8], s = 0.f;
#pragma unroll
    for (int e = 0; e < 8; e++) { prob[e] = expf(acc[e] - mx); s += prob[e]; }
    float inv = 1.f / s;
#pragma unroll
    for (int e = 0; e < 8; e++) prob[e] *= inv;
    int m1 = 0;
#pragma unroll
    for (int e = 1; e < 8; e++) if (prob[e] < prob[m1]) m1 = e;
    int m2 = -1;
#pragma unroll
    for (int e = 0; e < 8; e++)
      if (e != m1 && (m2 < 0 || prob[e] < prob[m2])) m2 = e;
#pragma unroll
    for (int e = 0; e < 8; e++)
      cw[(size_t)t * 8 + e] = (e == m1 || e == m2) ? 0.f : prob[e];
  }
}

// -------- all 27 weight transposes, one launch: fp32 [K,N] -> bf16 [N,K] --------
// XOR-swizzled LDS, stride 64. Element (k,n) stored at T[k*64 + (n ^ (k&56))]
// (ushort4 write stays contiguous: mask hits bits 3-5 only). Read of (k0+j, n)
// uses mask n^k0 since (k0+j)&56 == k0 for j<8. Read-instruction low-6 addr =
// (n_ + 32p) ^ k0 spans 64 distinct values across the wave -> 32 banks x 2
// lanes = conflict-free (m136). Thread decomposition identical to the proven
// round-3 version: n_ = tid>>3 (0..31), k0 = (tid&7)*8, p<2, n = n_ + 32p
// (round-6 failure was a broken decomposition here, not the swizzle math).
__global__ __launch_bounds__(256) void transpose_all(
    const float* __restrict__ wg, const float* __restrict__ wu,
    const float* __restrict__ wd, const float* __restrict__ wsg,
    const float* __restrict__ wsu, const float* __restrict__ wsd,
    unsigned short* __restrict__ wgT, unsigned short* __restrict__ wuT,
    unsigned short* __restrict__ wdT, unsigned short* __restrict__ wsgT,
    unsigned short* __restrict__ wsuT, unsigned short* __restrict__ wsdT) {
  __shared__ __align__(16) unsigned short T[64 * 64];
  const int z = blockIdx.z;
  const float* src; unsigned short* dst; int K, N;
  if (z < 8)       { src = wg  + (size_t)z * 1024 * 512;        dst = wgT + (size_t)z * 512 * 1024;        K = 1024; N = 512; }
  else if (z < 16) { src = wu  + (size_t)(z - 8) * 1024 * 512;  dst = wuT + (size_t)(z - 8) * 512 * 1024;  K = 1024; N = 512; }
  else if (z < 24) { src = wd  + (size_t)(z - 16) * 512 * 1024; dst = wdT + (size_t)(z - 16) * 1024 * 512; K = 512;  N = 1024; }
  else if (z == 24){ src = wsg; dst = wsgT; K = 1024; N = 1024; }
  else if (z == 25){ src = wsu; dst = wsuT; K = 1024; N = 1024; }
  else             { src = wsd; dst = wsdT; K = 1024; N = 1024; }
  const int bn = blockIdx.x * 64, bk = blockIdx.y * 64;
  if (bn >= N || bk >= K) return;
  const int tid = threadIdx.x;
  {
    const int r = tid >> 4;            // 0..15
    const int c = (tid & 15) * 4;      // 0..60
#pragma unroll
    for (int i = 0; i < 4; i++) {
      const int rr = r + i * 16;       // k-row 0..63
      float4 v = *(const float4*)(src + (size_t)(bk + rr) * N + bn + c);
      ushort4 o;
      o.x = f2b(v.x); o.y = f2b(v.y); o.z = f2b(v.z); o.w = f2b(v.w);
      *(ushort4*)(&T[rr * 64 + (c ^ (rr & 56))]) = o;
    }
  }
  __syncthreads();
  {
    const int n_ = tid >> 3;           // 0..31
    const int k0 = (tid & 7) * 8;      // 0..56 (bits 3-5 == its own xor mask)
#pragma unroll
    for (int p = 0; p < 2; p++) {
      const int n = n_ + p * 32;       // 0..63
      ushort8 o;
#pragma unroll
      for (int j = 0; j < 8; j++) o[j] = T[(k0 + j) * 64 + (n ^ k0)];
      *(ushort8*)(dst + (size_t)(bn + n) * K + bk + k0) = o;
    }
  }
}

// ------------- fused gate+up GEMM: H = cw * silu(X@Wg) * (X@Wu) -----------------
// (frozen: BM=256, BN=128, BK=64, 8 waves, dbuf 128KB LDS, 4 phases/K-tile,
// counted vmcnt(6), XOR swizzle, raw s_barrier, setprio, XCD n-ownership.)
#define VMCNT(N) asm volatile("s_waitcnt vmcnt(" #N ")" ::: "memory")
#define BARS() do { __builtin_amdgcn_s_barrier(); \
                    __builtin_amdgcn_sched_barrier(0); } while (0)

#define STG_I0(K, BS) do { \
  GLDS(a0 + (K),          sm + (BS) + wid * 512); \
  GLDS(a0 + (K) + 131072, sm + (BS) + 8192 + wid * 512); } while (0)
#define STG_I1(K, BS) do { \
  GLDS(bg0 + (K),        sm + (BS) + 16384 + wid * 1024); \
  GLDS(bg0 + (K) + 8192, sm + (BS) + 16384 + wid * 1024 + 512); } while (0)
#define STG_I2(K, BS) do { \
  GLDS(bu0 + (K),        sm + (BS) + 24576 + wid * 1024); \
  GLDS(bu0 + (K) + 8192, sm + (BS) + 24576 + wid * 1024 + 512); } while (0)
#define STG_I3(K, BS) do { \
  GLDS(a0 + (K) + 65536,  sm + (BS) + 4096 + wid * 512); \
  GLDS(a0 + (K) + 196608, sm + (BS) + 12288 + wid * 512); } while (0)

#define READ_A(DST, DB, H) do { _Pragma("unroll") \
  for (int mf = 0; mf < 4; ++mf) { \
    const int row_ = wm * 128 + (H) * 64 + mf * 16 + lr; \
    const int rb_ = (DB) + row_ * 64; const int rx_ = row_ & 7; \
    DST[mf][0] = *(const bf16x8*)(sm + rb_ + ((quad ^ rx_) << 3)); \
    DST[mf][1] = *(const bf16x8*)(sm + rb_ + (((4 + quad) ^ rx_) << 3)); \
  } } while (0)

#define READ_B(DST, DB, RG) do { _Pragma("unroll") \
  for (int nf = 0; nf < 2; ++nf) { \
    const int row_ = wn * 32 + nf * 16 + lr; \
    const int rb_ = (DB) + (RG) + row_ * 64; const int rx_ = row_ & 7; \
    DST[nf][0] = *(const bf16x8*)(sm + rb_ + ((quad ^ rx_) << 3)); \
    DST[nf][1] = *(const bf16x8*)(sm + rb_ + (((4 + quad) ^ rx_) << 3)); \
  } } while (0)

#define MM(ACC, AF, BF) do { \
  __builtin_amdgcn_s_setprio(1); \
  _Pragma("unroll") \
  for (int mf = 0; mf < 4; ++mf) { _Pragma("unroll") \
    for (int nf = 0; nf < 2; ++nf) { \
      ACC[mf][nf] = __builtin_amdgcn_mfma_f32_16x16x32_bf16( \
          AF[mf][0], BF[nf][0], ACC[mf][nf], 0, 0, 0); \
      ACC[mf][nf] = __builtin_amdgcn_mfma_f32_16x16x32_bf16( \
          AF[mf][1], BF[nf][1], ACC[mf][nf], 0, 0, 0); \
    } } \
  __builtin_amdgcn_s_setprio(0); } while (0)

__global__ __launch_bounds__(512, 2) void gemm_gu_fused(
    const unsigned short* __restrict__ X,
    const unsigned short* __restrict__ WgTe,
    const unsigned short* __restrict__ WgTs,
    const unsigned short* __restrict__ WuTe,
    const unsigned short* __restrict__ WuTs,
    unsigned short* __restrict__ H,
    const float* __restrict__ cw, int Mb) {
  __shared__ __align__(16) unsigned short sm[65536];
  const int tid = threadIdx.x;
  const int wid = tid >> 6, lane = tid & 63;
  const int lr = lane & 15, quad = lane >> 4;
  const int wm = wid >> 2, wn = wid & 3;

  int m_idx, n_idx;
  {
    const int lin = blockIdx.x;
    const int xcd = lin & 7;
    const int idx = lin >> 3;          // [0, Mb*5)
    m_idx = idx / 5;
    n_idx = xcd * 5 + (idx - m_idx * 5);
  }
  const int m0 = m_idx * 256;
  const int n0 = n_idx * 128;

  const unsigned short *Bg, *Bu;
  int eidx = -1;
  if (n0 < 4096) {
    eidx = n0 >> 9;
    size_t off = ((size_t)eidx * 512 + (n0 & 511)) * 1024;
    Bg = WgTe + off; Bu = WuTe + off;
  } else {
    size_t off = (size_t)(n0 - 4096) * 1024;
    Bg = WgTs + off; Bu = WuTs + off;
  }

  const int grow8 = lane >> 3;
  const int gcol = ((lane & 7) ^ grow8) << 3;
  const unsigned short* a0 =
      X + (size_t)(m0 + wid * 8 + grow8) * 1024 + gcol;
  const unsigned short* bg0 =
      Bg + (size_t)(wid * 16 + grow8) * 1024 + gcol;
  const unsigned short* bu0 =
      Bu + (size_t)(wid * 16 + grow8) * 1024 + gcol;

  floatx4 gg[2][4][2], uu[2][4][2];
#pragma unroll
  for (int h = 0; h < 2; h++)
#pragma unroll
    for (int mf = 0; mf < 4; mf++)
#pragma unroll
      for (int nf = 0; nf < 2; nf++) {
        gg[h][mf][nf] = (floatx4)0.f;
        uu[h][mf][nf] = (floatx4)0.f;
      }

  bf16x8 fA0[4][2], fA1[4][2], fBg[2][2], fBu[2][2];

  STG_I0(0, 0); STG_I1(0, 0); STG_I2(0, 0); STG_I3(0, 0);

  for (int t = 0; t < 15; ++t) {
    const int db = (t & 1) << 15;
    const int nb = 32768 - db;
    const int kn = (t + 1) * 64;
    STG_I0(kn, nb);
    VMCNT(6); BARS();
    READ_A(fA0, db, 0);
    READ_B(fBg, db, 16384);
    MM(gg[0], fA0, fBg);
    STG_I1(kn, nb);
    VMCNT(6); BARS();
    READ_B(fBu, db, 24576);
    MM(uu[0], fA0, fBu);
    STG_I2(kn, nb);
    VMCNT(6); BARS();
    READ_A(fA1, db, 1);
    MM(gg[1], fA1, fBg);
    STG_I3(kn, nb);
    BARS();
    MM(uu[1], fA1, fBu);
  }
  {
    const int db = 32768;
    VMCNT(4); BARS();
    READ_A(fA0, db, 0);
    READ_B(fBg, db, 16384);
    MM(gg[0], fA0, fBg);
    VMCNT(2); BARS();
    READ_B(fBu, db, 24576);
    MM(uu[0], fA0, fBu);
    VMCNT(0); BARS();
    READ_A(fA1, db, 1);
    MM(gg[1], fA1, fBg);
    MM(uu[1], fA1, fBu);
  }

#pragma unroll
  for (int h = 0; h < 2; h++) {
#pragma unroll
    for (int mf = 0; mf < 4; mf++) {
#pragma unroll
      for (int nf = 0; nf < 2; nf++) {
#pragma unroll
        for (int r = 0; r < 4; r++) {
          int row = m0 + wm * 128 + h * 64 + mf * 16 + quad * 4 + r;
          int col = n0 + wn * 32 + nf * 16 + lr;
          float g = gg[h][mf][nf][r];
          float u = uu[h][mf][nf][r];
          float s = (eidx >= 0) ? cw[(size_t)row * 8 + eidx] : 1.0f;
          float silu = g / (1.0f + __expf(-g));
          H[(size_t)row * 5120 + col] = f2b(s * silu * u);
        }
      }
    }
  }
}

// ---------------- down GEMM: Y[rows,1024] = H[rows,5120] @ Wd_cat (fp32 out) ----
// Round-3 proven config: quad-buffered, prefetch depth 3. BM=128, BN=128,
// BK=64, 512 thr (8 waves 2Mx4N), grid = (rows/128) x 8 = 256 blocks. 128KB
// LDS = 4 x (A 16KB + B 16KB). Tile t stages t+3; vmcnt(8) steady-state
// (before barrier), drain 8/8/4/0. XOR chunk-swizzle.
#define DN_STG(KN, SBUF) do { \
  GLDS(Ha + (size_t)(KN),          smD + (SBUF) + wid * 512); \
  GLDS(Ha + (size_t)(KN) + 327680, smD + (SBUF) + 4096 + wid * 512); \
  const unsigned short *b0p_, *b1p_; \
  if ((KN) < 4096) { \
    const unsigned short* be_ = WdTe + ((size_t)((KN) >> 9)) * (1024 * 512) + ((KN) & 511); \
    b0p_ = be_ + (size_t)bn0 * 512 + gcol; \
    b1p_ = be_ + (size_t)(bn0 + 64) * 512 + gcol; \
  } else { \
    b0p_ = WdTs + (size_t)bn0 * 1024 + ((KN) - 4096) + gcol; \
    b1p_ = WdTs + (size_t)(bn0 + 64) * 1024 + ((KN) - 4096) + gcol; \
  } \
  GLDS(b0p_, smD + (SBUF) + 8192 + wid * 512); \
  GLDS(b1p_, smD + (SBUF) + 12288 + wid * 512); } while (0)

#define DN_TILE(T, BUF, SBUF, DOSTG, VM) do { \
  VMCNT(VM); BARS(); \
  if (DOSTG) { DN_STG(((T) + 3) * 64, SBUF); } \
  bf16x8 af_[4][2], bf_[2][2]; \
  _Pragma("unroll") \
  for (int mt = 0; mt < 4; ++mt) { \
    const int row_ = wm * 64 + mt * 16 + lr; \
    const int rb_ = (BUF) + row_ * 64; const int rx_ = row_ & 7; \
    af_[mt][0] = *(const bf16x8*)(smD + rb_ + ((quad ^ rx_) << 3)); \
    af_[mt][1] = *(const bf16x8*)(smD + rb_ + (((4 + quad) ^ rx_) << 3)); \
  } \
  _Pragma("unroll") \
  for (int nt = 0; nt < 2; ++nt) { \
    const int row_ = wn * 32 + nt * 16 + lr; \
    const int rb_ = (BUF) + 8192 + row_ * 64; const int rx_ = row_ & 7; \
    bf_[nt][0] = *(const bf16x8*)(smD + rb_ + ((quad ^ rx_) << 3)); \
    bf_[nt][1] = *(const bf16x8*)(smD + rb_ + (((4 + quad) ^ rx_) << 3)); \
  } \
  __builtin_amdgcn_s_setprio(1); \
  _Pragma("unroll") \
  for (int kt = 0; kt < 2; ++kt) \
    _Pragma("unroll") \
    for (int mt = 0; mt < 4; ++mt) \
      _Pragma("unroll") \
      for (int nt = 0; nt < 2; ++nt) \
        acc[mt][nt] = __builtin_amdgcn_mfma_f32_16x16x32_bf16( \
            af_[mt][kt], bf_[nt][kt], acc[mt][nt], 0, 0, 0); \
  __builtin_amdgcn_s_setprio(0); } while (0)

__global__ __launch_bounds__(512, 2) void gemm_down(
    const unsigned short* __restrict__ H,
    const unsigned short* __restrict__ WdTe,
    const unsigned short* __restrict__ WdTs,
    float* __restrict__ Y, int Mb) {
  // 4 buffers x 16384 shorts: per buffer A [0,8192), B [8192,16384)
  __shared__ __align__(16) unsigned short smD[65536];
  const int tid = threadIdx.x;
  const int wid = tid >> 6, lane = tid & 63;
  const int lr = lane & 15, quad = lane >> 4;
  const int wm = wid >> 2, wn = wid & 3;
  int m_idx, n_idx;
  swizzle_mn(blockIdx.x, Mb, 8, m_idx, n_idx);
  const int m0 = m_idx * 128;
  const int n0 = n_idx * 128;

  const int grow8 = lane >> 3;
  const int gcol = ((lane & 7) ^ grow8) << 3;
  const unsigned short* Ha = H + (size_t)(m0 + wid * 8 + grow8) * 5120 + gcol;
  const int bn0 = n0 + wid * 8 + grow8;

  floatx4 acc[4][2];
#pragma unroll
  for (int i = 0; i < 4; i++)
#pragma unroll
    for (int j = 0; j < 2; j++) acc[i][j] = (floatx4)0.f;

  // prologue: tiles 0,1,2 -> buffers 0,1,2 (12 loads in flight)
  DN_STG(0, 0);
  DN_STG(64, 16384);
  DN_STG(128, 32768);

  // 80 K-tiles; main loop tiles 0..75 (19 x 4), staging t+3 (last stage = 78)
  for (int t = 0; t < 76; t += 4) {
    DN_TILE(t,     0,     49152, true, 8);
    DN_TILE(t + 1, 16384, 0,     true, 8);
    DN_TILE(t + 2, 32768, 16384, true, 8);
    DN_TILE(t + 3, 49152, 32768, true, 8);
  }
  // tail: 76 (stages 79), 77, 78, 79
  DN_TILE(76, 0,     49152, true,  8);
  DN_TILE(77, 16384, 0,     false, 8);
  DN_TILE(78, 32768, 0,     false, 4);
  DN_TILE(79, 49152, 0,     false, 0);

#pragma unroll
  for (int mt = 0; mt < 4; mt++)
#pragma unroll
    for (int nt = 0; nt < 2; nt++)
#pragma unroll
      for (int r = 0; r < 4; r++) {
        int row = m0 + wm * 64 + mt * 16 + quad * 4 + r;
        int col = n0 + wn * 32 + nt * 16 + lr;
        Y[(size_t)row * 1024 + col] = acc[mt][nt][r];
      }
}

extern "C" void kernel_launch(void* const* d_in, const int* in_sizes, int n_in,
                              void* d_out, int out_size, void* d_ws, size_t ws_size,
                              hipStream_t stream) {
  const float* hs  = (const float*)d_in[0];
  const float* rw  = (const float*)d_in[1];
  const float* wg  = (const float*)d_in[2];
  const float* wu  = (const float*)d_in[3];
  const float* wd  = (const float*)d_in[4];
  const float* wsg = (const float*)d_in[5];
  const float* wsu = (const float*)d_in[6];
  const float* wsd = (const float*)d_in[7];
  float* out = (float*)d_out;

  char* p = (char*)d_ws;
  float* cw = (float*)p;                    p += (size_t)4096 * 8 * 4;
  unsigned short* Xb   = (unsigned short*)p; p += (size_t)4096 * 1024 * 2;
  unsigned short* wgT  = (unsigned short*)p; p += (size_t)8 * 512 * 1024 * 2;
  unsigned short* wuT  = (unsigned short*)p; p += (size_t)8 * 512 * 1024 * 2;
  unsigned short* wsgT = (unsigned short*)p; p += (size_t)1024 * 1024 * 2;
  unsigned short* wsuT = (unsigned short*)p; p += (size_t)1024 * 1024 * 2;
  unsigned short* wdT  = (unsigned short*)p; p += (size_t)8 * 1024 * 512 * 2;
  unsigned short* wsdT = (unsigned short*)p; p += (size_t)1024 * 1024 * 2;
  unsigned short* GH   = (unsigned short*)p;
  const size_t base_bytes = (size_t)(p - (char*)d_ws);

  int chunks = 8;
  for (int c = 1; c <= 8; c *= 2) {
    size_t gh_bytes = ((size_t)4096 / c) * 5120 * 2;
    if (base_bytes + gh_bytes <= ws_size) { chunks = c; break; }
  }
  const int rows = 4096 / chunks;
  const int Mb = rows / 128;     // gemm_down 128-row tiles
  const int MbG = rows / 256;    // gemm_gu 256-row tiles

  router_cvt<<<1024, 256, 0, stream>>>(hs, rw, cw, Xb);
  transpose_all<<<dim3(16, 16, 27), 256, 0, stream>>>(
      wg, wu, wd, wsg, wsu, wsd, wgT, wuT, wdT, wsgT, wsuT, wsdT);

  for (int c = 0; c < chunks; c++) {
    const unsigned short* Xc = Xb + (size_t)c * rows * 1024;
    const float* cwc = cw + (size_t)c * rows * 8;
    float* outc = out + (size_t)c * rows * 1024;
    gemm_gu_fused<<<MbG * 40, 512, 0, stream>>>(
        Xc, wgT, wsgT, wuT, wsuT, GH, cwc, MbG);
    gemm_down<<<Mb * 8, 512, 0, stream>>>(GH, wdT, wsdT, outc, Mb);
  }
}

// Round 8
// 293.330 us; speedup vs baseline: 1.1029x; 1.0142x over previous
//
#include <hip/hip_runtime.h>

typedef __attribute__((ext_vector_type(8))) short bf16x8;
typedef __attribute__((ext_vector_type(8))) unsigned short ushort8;
typedef __attribute__((ext_vector_type(4))) float floatx4;

static __device__ __forceinline__ unsigned short f2b(float f) {
  union { float f; unsigned int i; } v; v.f = f;
  unsigned int x = v.i;
  return (unsigned short)((x + 0x7fffu + ((x >> 16) & 1u)) >> 16);
}

#define GLDS(gp, lp) \
  __builtin_amdgcn_global_load_lds( \
      (const __attribute__((address_space(1))) unsigned int*)(gp), \
      (__attribute__((address_space(3))) unsigned int*)(lp), 16, 0, 0)

static __device__ __forceinline__ void swizzle_mn(int lin, int Mb, int Nb,
                                                  int& m_idx, int& n_idx) {
  if ((Mb & 7) == 0) {
    int xcd = lin & 7;
    int idx = lin >> 3;
    int nstrips = Mb >> 3;
    m_idx = (idx % nstrips) * 8 + xcd;
    n_idx = idx / nstrips;
  } else {
    m_idx = lin % Mb;
    n_idx = lin / Mb;
  }
}

// -------- fused router + fp32->bf16 convert (one pass over hidden_states) ------
__global__ __launch_bounds__(256) void router_cvt(
    const float* __restrict__ X, const float* __restrict__ RW,
    float* __restrict__ cw, unsigned short* __restrict__ Xb) {
  const int tid = threadIdx.x;
  const int wid = tid >> 6, lane = tid & 63;
  const int t = blockIdx.x * 4 + wid;
  const float* xp = X + (size_t)t * 1024;
  unsigned short* xo = Xb + (size_t)t * 1024;
  float acc[8];
#pragma unroll
  for (int e = 0; e < 8; e++) acc[e] = 0.f;
#pragma unroll
  for (int i = 0; i < 4; i++) {
    const int d0 = i * 256 + lane * 4;
    float4 v = *(const float4*)(xp + d0);
    ushort4 o;
    o.x = f2b(v.x); o.y = f2b(v.y); o.z = f2b(v.z); o.w = f2b(v.w);
    *(ushort4*)(xo + d0) = o;
    const float xv[4] = {v.x, v.y, v.z, v.w};
#pragma unroll
    for (int j = 0; j < 4; j++) {
      const float* r = RW + (size_t)(d0 + j) * 8;
      float4 r0 = *(const float4*)r;
      float4 r1 = *(const float4*)(r + 4);
      acc[0] += xv[j] * r0.x; acc[1] += xv[j] * r0.y;
      acc[2] += xv[j] * r0.z; acc[3] += xv[j] * r0.w;
      acc[4] += xv[j] * r1.x; acc[5] += xv[j] * r1.y;
      acc[6] += xv[j] * r1.z; acc[7] += xv[j] * r1.w;
    }
  }
#pragma unroll
  for (int m = 1; m < 64; m <<= 1) {
#pragma unroll
    for (int e = 0; e < 8; e++) acc[e] += __shfl_xor(acc[e], m);
  }
  if (lane == 0) {
    float mx = acc[0];
#pragma unroll
    for (int e = 1; e < 8; e++) mx = fmaxf(mx, acc[e]);
    float prob[8], s = 0.f;
#pragma unroll
    for (int e = 0; e < 8; e++) { prob[e] = expf(acc[e] - mx); s += prob[e]; }
    float inv = 1.f / s;
#pragma unroll
    for (int e = 0; e < 8; e++) prob[e] *= inv;
    int m1 = 0;
#pragma unroll
    for (int e = 1; e < 8; e++) if (prob[e] < prob[m1]) m1 = e;
    int m2 = -1;
#pragma unroll
    for (int e = 0; e < 8; e++)
      if (e != m1 && (m2 < 0 || prob[e] < prob[m2])) m2 = e;
#pragma unroll
    for (int e = 0; e < 8; e++)
      cw[(size_t)t * 8 + e] = (e == m1 || e == m2) ? 0.f : prob[e];
  }
}

// -------- all 27 weight transposes, one launch: fp32 [K,N] -> bf16 [N,K] --------
// XOR-swizzled LDS, stride 64 (proven round 7): (k,n) at T[k*64 + (n^(k&56))];
// read of (k0+j, n) uses mask n^k0. Read conflict-free, write 4-way (same as
// the old padded layout's write).
__global__ __launch_bounds__(256) void transpose_all(
    const float* __restrict__ wg, const float* __restrict__ wu,
    const float* __restrict__ wd, const float* __restrict__ wsg,
    const float* __restrict__ wsu, const float* __restrict__ wsd,
    unsigned short* __restrict__ wgT, unsigned short* __restrict__ wuT,
    unsigned short* __restrict__ wdT, unsigned short* __restrict__ wsgT,
    unsigned short* __restrict__ wsuT, unsigned short* __restrict__ wsdT) {
  __shared__ __align__(16) unsigned short T[64 * 64];
  const int z = blockIdx.z;
  const float* src; unsigned short* dst; int K, N;
  if (z < 8)       { src = wg  + (size_t)z * 1024 * 512;        dst = wgT + (size_t)z * 512 * 1024;        K = 1024; N = 512; }
  else if (z < 16) { src = wu  + (size_t)(z - 8) * 1024 * 512;  dst = wuT + (size_t)(z - 8) * 512 * 1024;  K = 1024; N = 512; }
  else if (z < 24) { src = wd  + (size_t)(z - 16) * 512 * 1024; dst = wdT + (size_t)(z - 16) * 1024 * 512; K = 512;  N = 1024; }
  else if (z == 24){ src = wsg; dst = wsgT; K = 1024; N = 1024; }
  else if (z == 25){ src = wsu; dst = wsuT; K = 1024; N = 1024; }
  else             { src = wsd; dst = wsdT; K = 1024; N = 1024; }
  const int bn = blockIdx.x * 64, bk = blockIdx.y * 64;
  if (bn >= N || bk >= K) return;
  const int tid = threadIdx.x;
  {
    const int r = tid >> 4;            // 0..15
    const int c = (tid & 15) * 4;      // 0..60
#pragma unroll
    for (int i = 0; i < 4; i++) {
      const int rr = r + i * 16;       // k-row 0..63
      float4 v = *(const float4*)(src + (size_t)(bk + rr) * N + bn + c);
      ushort4 o;
      o.x = f2b(v.x); o.y = f2b(v.y); o.z = f2b(v.z); o.w = f2b(v.w);
      *(ushort4*)(&T[rr * 64 + (c ^ (rr & 56))]) = o;
    }
  }
  __syncthreads();
  {
    const int n_ = tid >> 3;           // 0..31
    const int k0 = (tid & 7) * 8;      // 0..56
#pragma unroll
    for (int p = 0; p < 2; p++) {
      const int n = n_ + p * 32;       // 0..63
      ushort8 o;
#pragma unroll
      for (int j = 0; j < 8; j++) o[j] = T[(k0 + j) * 64 + (n ^ k0)];
      *(ushort8*)(dst + (size_t)(bn + n) * K + bk + k0) = o;
    }
  }
}

// ------------- fused gate+up GEMM: H = cw * silu(X@Wg) * (X@Wu) -----------------
// Frozen structure (round 1). XCD swizzle reverted to the round-1/3 m-ownership
// form (n-ownership was time-neutral in gu and correlated with a ~10us total
// drift; revert for clean attribution).
#define VMCNT(N) asm volatile("s_waitcnt vmcnt(" #N ")" ::: "memory")
#define BARS() do { __builtin_amdgcn_s_barrier(); \
                    __builtin_amdgcn_sched_barrier(0); } while (0)

#define STG_I0(K, BS) do { \
  GLDS(a0 + (K),          sm + (BS) + wid * 512); \
  GLDS(a0 + (K) + 131072, sm + (BS) + 8192 + wid * 512); } while (0)
#define STG_I1(K, BS) do { \
  GLDS(bg0 + (K),        sm + (BS) + 16384 + wid * 1024); \
  GLDS(bg0 + (K) + 8192, sm + (BS) + 16384 + wid * 1024 + 512); } while (0)
#define STG_I2(K, BS) do { \
  GLDS(bu0 + (K),        sm + (BS) + 24576 + wid * 1024); \
  GLDS(bu0 + (K) + 8192, sm + (BS) + 24576 + wid * 1024 + 512); } while (0)
#define STG_I3(K, BS) do { \
  GLDS(a0 + (K) + 65536,  sm + (BS) + 4096 + wid * 512); \
  GLDS(a0 + (K) + 196608, sm + (BS) + 12288 + wid * 512); } while (0)

#define READ_A(DST, DB, H) do { _Pragma("unroll") \
  for (int mf = 0; mf < 4; ++mf) { \
    const int row_ = wm * 128 + (H) * 64 + mf * 16 + lr; \
    const int rb_ = (DB) + row_ * 64; const int rx_ = row_ & 7; \
    DST[mf][0] = *(const bf16x8*)(sm + rb_ + ((quad ^ rx_) << 3)); \
    DST[mf][1] = *(const bf16x8*)(sm + rb_ + (((4 + quad) ^ rx_) << 3)); \
  } } while (0)

#define READ_B(DST, DB, RG) do { _Pragma("unroll") \
  for (int nf = 0; nf < 2; ++nf) { \
    const int row_ = wn * 32 + nf * 16 + lr; \
    const int rb_ = (DB) + (RG) + row_ * 64; const int rx_ = row_ & 7; \
    DST[nf][0] = *(const bf16x8*)(sm + rb_ + ((quad ^ rx_) << 3)); \
    DST[nf][1] = *(const bf16x8*)(sm + rb_ + (((4 + quad) ^ rx_) << 3)); \
  } } while (0)

#define MM(ACC, AF, BF) do { \
  __builtin_amdgcn_s_setprio(1); \
  _Pragma("unroll") \
  for (int mf = 0; mf < 4; ++mf) { _Pragma("unroll") \
    for (int nf = 0; nf < 2; ++nf) { \
      ACC[mf][nf] = __builtin_amdgcn_mfma_f32_16x16x32_bf16( \
          AF[mf][0], BF[nf][0], ACC[mf][nf], 0, 0, 0); \
      ACC[mf][nf] = __builtin_amdgcn_mfma_f32_16x16x32_bf16( \
          AF[mf][1], BF[nf][1], ACC[mf][nf], 0, 0, 0); \
    } } \
  __builtin_amdgcn_s_setprio(0); } while (0)

__global__ __launch_bounds__(512, 2) void gemm_gu_fused(
    const unsigned short* __restrict__ X,
    const unsigned short* __restrict__ WgTe,
    const unsigned short* __restrict__ WgTs,
    const unsigned short* __restrict__ WuTe,
    const unsigned short* __restrict__ WuTs,
    unsigned short* __restrict__ H,
    const float* __restrict__ cw, int Mb) {
  __shared__ __align__(16) unsigned short sm[65536];
  const int tid = threadIdx.x;
  const int wid = tid >> 6, lane = tid & 63;
  const int lr = lane & 15, quad = lane >> 4;
  const int wm = wid >> 2, wn = wid & 3;

  int m_idx, n_idx;
  {
    int lin = blockIdx.x;
    if ((Mb & 7) == 0) {
      int xcd = lin & 7, idx = lin >> 3;
      n_idx = idx % 40;
      m_idx = (idx / 40) * 8 + xcd;
    } else {
      m_idx = lin % Mb;
      n_idx = lin / Mb;
    }
  }
  const int m0 = m_idx * 256;
  const int n0 = n_idx * 128;

  const unsigned short *Bg, *Bu;
  int eidx = -1;
  if (n0 < 4096) {
    eidx = n0 >> 9;
    size_t off = ((size_t)eidx * 512 + (n0 & 511)) * 1024;
    Bg = WgTe + off; Bu = WuTe + off;
  } else {
    size_t off = (size_t)(n0 - 4096) * 1024;
    Bg = WgTs + off; Bu = WuTs + off;
  }

  const int grow8 = lane >> 3;
  const int gcol = ((lane & 7) ^ grow8) << 3;
  const unsigned short* a0 =
      X + (size_t)(m0 + wid * 8 + grow8) * 1024 + gcol;
  const unsigned short* bg0 =
      Bg + (size_t)(wid * 16 + grow8) * 1024 + gcol;
  const unsigned short* bu0 =
      Bu + (size_t)(wid * 16 + grow8) * 1024 + gcol;

  floatx4 gg[2][4][2], uu[2][4][2];
#pragma unroll
  for (int h = 0; h < 2; h++)
#pragma unroll
    for (int mf = 0; mf < 4; mf++)
#pragma unroll
      for (int nf = 0; nf < 2; nf++) {
        gg[h][mf][nf] = (floatx4)0.f;
        uu[h][mf][nf] = (floatx4)0.f;
      }

  bf16x8 fA0[4][2], fA1[4][2], fBg[2][2], fBu[2][2];

  STG_I0(0, 0); STG_I1(0, 0); STG_I2(0, 0); STG_I3(0, 0);

  for (int t = 0; t < 15; ++t) {
    const int db = (t & 1) << 15;
    const int nb = 32768 - db;
    const int kn = (t + 1) * 64;
    STG_I0(kn, nb);
    VMCNT(6); BARS();
    READ_A(fA0, db, 0);
    READ_B(fBg, db, 16384);
    MM(gg[0], fA0, fBg);
    STG_I1(kn, nb);
    VMCNT(6); BARS();
    READ_B(fBu, db, 24576);
    MM(uu[0], fA0, fBu);
    STG_I2(kn, nb);
    VMCNT(6); BARS();
    READ_A(fA1, db, 1);
    MM(gg[1], fA1, fBg);
    STG_I3(kn, nb);
    BARS();
    MM(uu[1], fA1, fBu);
  }
  {
    const int db = 32768;
    VMCNT(4); BARS();
    READ_A(fA0, db, 0);
    READ_B(fBg, db, 16384);
    MM(gg[0], fA0, fBg);
    VMCNT(2); BARS();
    READ_B(fBu, db, 24576);
    MM(uu[0], fA0, fBu);
    VMCNT(0); BARS();
    READ_A(fA1, db, 1);
    MM(gg[1], fA1, fBg);
    MM(uu[1], fA1, fBu);
  }

#pragma unroll
  for (int h = 0; h < 2; h++) {
#pragma unroll
    for (int mf = 0; mf < 4; mf++) {
#pragma unroll
      for (int nf = 0; nf < 2; nf++) {
#pragma unroll
        for (int r = 0; r < 4; r++) {
          int row = m0 + wm * 128 + h * 64 + mf * 16 + quad * 4 + r;
          int col = n0 + wn * 32 + nf * 16 + lr;
          float g = gg[h][mf][nf][r];
          float u = uu[h][mf][nf][r];
          float s = (eidx >= 0) ? cw[(size_t)row * 8 + eidx] : 1.0f;
          float silu = g / (1.0f + __expf(-g));
          H[(size_t)row * 5120 + col] = f2b(s * silu * u);
        }
      }
    }
  }
}

// ---------------- down GEMM: Y[rows,1024] = H[rows,5120] @ Wd_cat (fp32 out) ----
// Round 8: residency experiment. BM=128, BN=64, BK=64, 512 thr (8 waves 4Mx2N),
// grid = (rows/128) x 16 = 512 blocks -> 2 blocks/CU (72KB LDS, lb(512,4)).
// Full K=5120 per block (no split-K, no atomics). Triple-buffered, prefetch
// depth 2: 3 GLDS lines/tile (A x2, B x1), steady vmcnt(3) (one tile = 3 lines
// in flight), peel 3/0. XOR chunk-swizzle identical to gu. Co-resident block
// covers vmcnt/barrier stalls (the piece round-5's bundled experiment broke).
#define DN_STG(KN, SBUF) do { \
  GLDS(Ha + (size_t)(KN),          smD + (SBUF) + wid * 512); \
  GLDS(Ha + (size_t)(KN) + 327680, smD + (SBUF) + 4096 + wid * 512); \
  const unsigned short* b0p_; \
  if ((KN) < 4096) { \
    b0p_ = WdTe + ((size_t)((KN) >> 9)) * (1024 * 512) + ((KN) & 511) \
         + (size_t)bn0 * 512 + gcol; \
  } else { \
    b0p_ = WdTs + (size_t)bn0 * 1024 + ((KN) - 4096) + gcol; \
  } \
  GLDS(b0p_, smD + (SBUF) + 8192 + wid * 512); } while (0)

#define DN_TILE(T, BUF, SBUF, DOSTG, VM) do { \
  VMCNT(VM); BARS(); \
  if (DOSTG) { DN_STG(((T) + 2) * 64, SBUF); } \
  bf16x8 af_[2][2], bf_[2][2]; \
  _Pragma("unroll") \
  for (int mt = 0; mt < 2; ++mt) { \
    const int row_ = wm * 32 + mt * 16 + lr; \
    const int rb_ = (BUF) + row_ * 64; const int rx_ = row_ & 7; \
    af_[mt][0] = *(const bf16x8*)(smD + rb_ + ((quad ^ rx_) << 3)); \
    af_[mt][1] = *(const bf16x8*)(smD + rb_ + (((4 + quad) ^ rx_) << 3)); \
  } \
  _Pragma("unroll") \
  for (int nt = 0; nt < 2; ++nt) { \
    const int row_ = wn * 32 + nt * 16 + lr; \
    const int rb_ = (BUF) + 8192 + row_ * 64; const int rx_ = row_ & 7; \
    bf_[nt][0] = *(const bf16x8*)(smD + rb_ + ((quad ^ rx_) << 3)); \
    bf_[nt][1] = *(const bf16x8*)(smD + rb_ + (((4 + quad) ^ rx_) << 3)); \
  } \
  __builtin_amdgcn_s_setprio(1); \
  _Pragma("unroll") \
  for (int kt = 0; kt < 2; ++kt) \
    _Pragma("unroll") \
    for (int mt = 0; mt < 2; ++mt) \
      _Pragma("unroll") \
      for (int nt = 0; nt < 2; ++nt) \
        acc[mt][nt] = __builtin_amdgcn_mfma_f32_16x16x32_bf16( \
            af_[mt][kt], bf_[nt][kt], acc[mt][nt], 0, 0, 0); \
  __builtin_amdgcn_s_setprio(0); } while (0)

__global__ __launch_bounds__(512, 4) void gemm_down(
    const unsigned short* __restrict__ H,
    const unsigned short* __restrict__ WdTe,
    const unsigned short* __restrict__ WdTs,
    float* __restrict__ Y, int Mb) {
  // 3 buffers x 12288 shorts (24KB): per buffer A [0,8192), B [8192,12288)
  __shared__ __align__(16) unsigned short smD[36864];
  const int tid = threadIdx.x;
  const int wid = tid >> 6, lane = tid & 63;
  const int lr = lane & 15, quad = lane >> 4;
  const int wm = wid >> 1, wn = wid & 1;   // 4M x 2N
  int m_idx, n_idx;
  swizzle_mn(blockIdx.x, Mb, 16, m_idx, n_idx);
  const int m0 = m_idx * 128;
  const int n0 = n_idx * 64;

  const int grow8 = lane >> 3;
  const int gcol = ((lane & 7) ^ grow8) << 3;
  const unsigned short* Ha = H + (size_t)(m0 + wid * 8 + grow8) * 5120 + gcol;
  const int bn0 = n0 + wid * 8 + grow8;

  floatx4 acc[2][2];
#pragma unroll
  for (int i = 0; i < 2; i++)
#pragma unroll
    for (int j = 0; j < 2; j++) acc[i][j] = (floatx4)0.f;

  // prologue: tiles 0,1 -> buffers 0,1 (6 lines in flight)
  DN_STG(0, 0);
  DN_STG(64, 12288);

  // 80 K-tiles; main loop tiles 0..77 (26 x 3), staging t+2 (last stage = 79)
  for (int t = 0; t < 78; t += 3) {
    DN_TILE(t,     0,     24576, true, 3);
    DN_TILE(t + 1, 12288, 0,     true, 3);
    DN_TILE(t + 2, 24576, 12288, true, 3);
  }
  // tail: 78 (buf 0), 79 (buf 1)
  DN_TILE(78, 0,     0, false, 3);
  DN_TILE(79, 12288, 0, false, 0);

#pragma unroll
  for (int mt = 0; mt < 2; mt++)
#pragma unroll
    for (int nt = 0; nt < 2; nt++)
#pragma unroll
      for (int r = 0; r < 4; r++) {
        int row = m0 + wm * 32 + mt * 16 + quad * 4 + r;
        int col = n0 + wn * 32 + nt * 16 + lr;
        Y[(size_t)row * 1024 + col] = acc[mt][nt][r];
      }
}

extern "C" void kernel_launch(void* const* d_in, const int* in_sizes, int n_in,
                              void* d_out, int out_size, void* d_ws, size_t ws_size,
                              hipStream_t stream) {
  const float* hs  = (const float*)d_in[0];
  const float* rw  = (const float*)d_in[1];
  const float* wg  = (const float*)d_in[2];
  const float* wu  = (const float*)d_in[3];
  const float* wd  = (const float*)d_in[4];
  const float* wsg = (const float*)d_in[5];
  const float* wsu = (const float*)d_in[6];
  const float* wsd = (const float*)d_in[7];
  float* out = (float*)d_out;

  char* p = (char*)d_ws;
  float* cw = (float*)p;                    p += (size_t)4096 * 8 * 4;
  unsigned short* Xb   = (unsigned short*)p; p += (size_t)4096 * 1024 * 2;
  unsigned short* wgT  = (unsigned short*)p; p += (size_t)8 * 512 * 1024 * 2;
  unsigned short* wuT  = (unsigned short*)p; p += (size_t)8 * 512 * 1024 * 2;
  unsigned short* wsgT = (unsigned short*)p; p += (size_t)1024 * 1024 * 2;
  unsigned short* wsuT = (unsigned short*)p; p += (size_t)1024 * 1024 * 2;
  unsigned short* wdT  = (unsigned short*)p; p += (size_t)8 * 1024 * 512 * 2;
  unsigned short* wsdT = (unsigned short*)p; p += (size_t)1024 * 1024 * 2;
  unsigned short* GH   = (unsigned short*)p;
  const size_t base_bytes = (size_t)(p - (char*)d_ws);

  int chunks = 8;
  for (int c = 1; c <= 8; c *= 2) {
    size_t gh_bytes = ((size_t)4096 / c) * 5120 * 2;
    if (base_bytes + gh_bytes <= ws_size) { chunks = c; break; }
  }
  const int rows = 4096 / chunks;
  const int Mb = rows / 128;     // gemm_down 128-row tiles
  const int MbG = rows / 256;    // gemm_gu 256-row tiles

  router_cvt<<<1024, 256, 0, stream>>>(hs, rw, cw, Xb);
  transpose_all<<<dim3(16, 16, 27), 256, 0, stream>>>(
      wg, wu, wd, wsg, wsu, wsd, wgT, wuT, wdT, wsgT, wsuT, wsdT);

  for (int c = 0; c < chunks; c++) {
    const unsigned short* Xc = Xb + (size_t)c * rows * 1024;
    const float* cwc = cw + (size_t)c * rows * 8;
    float* outc = out + (size_t)c * rows * 1024;
    gemm_gu_fused<<<MbG * 40, 512, 0, stream>>>(
        Xc, wgT, wsgT, wuT, wsuT, GH, cwc, MbG);
    gemm_down<<<Mb * 16, 512, 0, stream>>>(GH, wdT, wsdT, outc, Mb);
  }
}